// Round 9
// baseline (318.982 us; speedup 1.0000x reference)
//
#include <hip/hip_runtime.h>
#include <hip/hip_fp16.h>
#include <math.h>

#define IN_DIM 512
#define EMBED 128
#define OUT_DIM 64
#define NBPAD 256      // padded bucket count (actual NB = ceil(N/256) = 196)
#define SEGSH 12       // 4096 edges per bin block
#define CAP_LDS 12288  // build LDS capacity (mean 8430, +42 sigma)

typedef __attribute__((ext_vector_type(8))) short bf16x8;
typedef __attribute__((ext_vector_type(4))) float f32x4;

__device__ __forceinline__ float lrelu(float v, float s) { return v > 0.f ? v : v * s; }

__device__ __forceinline__ float readlane_f(float v, int l) {
  return __int_as_float(__builtin_amdgcn_readlane(__float_as_int(v), l));
}

__device__ __forceinline__ unsigned short f2bf(float f) {
  unsigned int u = __float_as_uint(f);
  u += 0x7fff + ((u >> 16) & 1);  // RTNE
  return (unsigned short)(u >> 16);
}
__device__ __forceinline__ float bf2f(unsigned short h) {
  return __uint_as_float(((unsigned int)h) << 16);
}

// monotone float<->uint key (for atomicMax on floats)
__device__ __forceinline__ unsigned int fkey(float f) {
  unsigned int b = __float_as_uint(f);
  return b ^ ((unsigned int)((int)b >> 31) | 0x80000000u);
}
__device__ __forceinline__ float funkey(unsigned int k) {
  unsigned int b = k ^ ((k & 0x80000000u) ? 0x80000000u : 0xFFFFFFFFu);
  return __uint_as_float(b);
}

// packed f32x2 -> bf16x2 (low half = src0, high half = src1)
__device__ __forceinline__ unsigned int cvt_pk_bf16(float a, float b) {
  unsigned int r;
  asm("v_cvt_pk_bf16_f32 %0, %1, %2" : "=v"(r) : "v"(a), "v"(b));
  return r;
}

// async global->LDS 16B DMA (dest = wave base + lane*16, src per-lane)
__device__ __forceinline__ void gl_lds16(const void* g, void* l) {
  __builtin_amdgcn_global_load_lds(
      (const __attribute__((address_space(1))) unsigned int*)g,
      (__attribute__((address_space(3))) unsigned int*)l, 16, 0, 0);
}

// ---------------------------------------------------------------------------
// Prep: split Wd (65536) AND Wg (8192) fp32 -> bf16 hi/lo planes. One launch.
// ---------------------------------------------------------------------------
__global__ __launch_bounds__(256) void split_w_kernel(
    const float* __restrict__ Wd, unsigned short* __restrict__ Wdh,
    unsigned short* __restrict__ Wdl, const float* __restrict__ Wg,
    unsigned short* __restrict__ Wgh, unsigned short* __restrict__ Wgl) {
  int i = (blockIdx.x * 256 + threadIdx.x) * 4;
  const float* W;
  unsigned short *Wh, *Wl;
  int base;
  if (i < EMBED * IN_DIM) {
    W = Wd; Wh = Wdh; Wl = Wdl; base = i;
  } else {
    base = i - EMBED * IN_DIM;
    if (base >= OUT_DIM * EMBED) return;
    W = Wg; Wh = Wgh; Wl = Wgl;
  }
  float4 v = *(const float4*)(W + base);
  unsigned int h0 = cvt_pk_bf16(v.x, v.y);
  unsigned int h1 = cvt_pk_bf16(v.z, v.w);
  float r0 = v.x - __uint_as_float(h0 << 16);
  float r1 = v.y - __uint_as_float(h0 & 0xffff0000u);
  float r2 = v.z - __uint_as_float(h1 << 16);
  float r3 = v.w - __uint_as_float(h1 & 0xffff0000u);
  unsigned int l0 = cvt_pk_bf16(r0, r1);
  unsigned int l1 = cvt_pk_bf16(r2, r3);
  *(uint2*)(Wh + base) = make_uint2(h0, h1);
  *(uint2*)(Wl + base) = make_uint2(l0, l1);
}

// ---------------------------------------------------------------------------
// K1 (MFMA split-bf16): h = leaky_relu(x @ Wd^T + bd, 0.01)
// R6 4-wave version (best measured). Prefetch-before-compute, B dbuf via
// global_load_lds (swizzled src), A global->reg. Epilogue packs h split-bf16.
// ---------------------------------------------------------------------------
__global__ __launch_bounds__(256) void gemm1_mfma_kernel(
    const float* __restrict__ x, const unsigned short* __restrict__ Wdh,
    const unsigned short* __restrict__ Wdl, const float* __restrict__ bd,
    unsigned int* __restrict__ hp, int N) {
  __shared__ __align__(16) unsigned char Bhs[2][8192];
  __shared__ __align__(16) unsigned char Bls[2][8192];

  const int tid = threadIdx.x;
  const int lane = tid & 63;
  const int wid = tid >> 6;   // 0..3, wave owns rows wid*32..+32
  const int mblk = blockIdx.x * 128;
  const int quad = lane >> 4;
  const int l15 = lane & 15;

  const float* aptr[2];
#pragma unroll
  for (int mi = 0; mi < 2; ++mi) {
    int rg = mblk + wid * 32 + mi * 16 + l15;
    if (rg >= N) rg = N - 1;  // clamp; junk rows masked at store
    aptr[mi] = x + (size_t)rg * IN_DIM + quad * 8;
  }
  float4 tc[2][2];
  auto loadA = [&](int k0) {
#pragma unroll
    for (int mi = 0; mi < 2; ++mi) {
      tc[mi][0] = *(const float4*)(aptr[mi] + k0);
      tc[mi][1] = *(const float4*)(aptr[mi] + k0 + 4);
    }
  };

  const char* bsrcH[2];
  const char* bsrcL[2];
  int bdst[2];
#pragma unroll
  for (int i = 0; i < 2; ++i) {
    int chunk = i * 256 + tid;
    int row = chunk >> 2, ch = chunk & 3;
    int cs = ch ^ ((row >> 1) & 3);  // inverse-swizzled source chunk
    size_t srcoff = (size_t)row * (IN_DIM * 2) + (cs << 4);
    bsrcH[i] = (const char*)Wdh + srcoff;
    bsrcL[i] = (const char*)Wdl + srcoff;
    bdst[i] = chunk * 16;
  }
  auto stageB = [&](int buf, int k0) {
    const size_t kb = (size_t)k0 * 2;
#pragma unroll
    for (int i = 0; i < 2; ++i) {
      gl_lds16(bsrcH[i] + kb, Bhs[buf] + bdst[i]);
      gl_lds16(bsrcL[i] + kb, Bls[buf] + bdst[i]);
    }
  };

  int boff[8];
#pragma unroll
  for (int ni = 0; ni < 8; ++ni) {
    int row = ni * 16 + l15;
    boff[ni] = row * 64 + ((quad ^ ((row >> 1) & 3)) << 4);
  }

  f32x4 acc[2][8];
#pragma unroll
  for (int i = 0; i < 2; ++i)
#pragma unroll
    for (int j = 0; j < 8; ++j) acc[i][j] = (f32x4){0.f, 0.f, 0.f, 0.f};

  stageB(0, 0);
  loadA(0);
  __syncthreads();

#pragma unroll 2
  for (int s = 0; s < IN_DIM / 32; ++s) {
    const int buf = s & 1;
    if (s + 1 < IN_DIM / 32) stageB(buf ^ 1, (s + 1) * 32);

    bf16x8 AH[2], AL[2];
#pragma unroll
    for (int mi = 0; mi < 2; ++mi) {
      float av[8] = {tc[mi][0].x, tc[mi][0].y, tc[mi][0].z, tc[mi][0].w,
                     tc[mi][1].x, tc[mi][1].y, tc[mi][1].z, tc[mi][1].w};
      union { unsigned int u[4]; bf16x8 v; } H, L;
#pragma unroll
      for (int i = 0; i < 4; ++i) {
        unsigned int hpk = cvt_pk_bf16(av[2 * i], av[2 * i + 1]);
        float q0 = av[2 * i] - __uint_as_float(hpk << 16);
        float q1 = av[2 * i + 1] - __uint_as_float(hpk & 0xffff0000u);
        H.u[i] = hpk;
        L.u[i] = cvt_pk_bf16(q0, q1);
      }
      AH[mi] = H.v;
      AL[mi] = L.v;
    }
    if (s + 1 < IN_DIM / 32) loadA((s + 1) * 32);

#pragma unroll
    for (int hf = 0; hf < 2; ++hf) {
      bf16x8 BH[4], BL[4];
#pragma unroll
      for (int j = 0; j < 4; ++j) {
        BH[j] = *(const bf16x8*)(Bhs[buf] + boff[hf * 4 + j]);
        BL[j] = *(const bf16x8*)(Bls[buf] + boff[hf * 4 + j]);
      }
#pragma unroll
      for (int mi = 0; mi < 2; ++mi)
#pragma unroll
        for (int j = 0; j < 4; ++j) {
          int ni = hf * 4 + j;
          acc[mi][ni] = __builtin_amdgcn_mfma_f32_16x16x32_bf16(AH[mi], BH[j], acc[mi][ni], 0, 0, 0);
          acc[mi][ni] = __builtin_amdgcn_mfma_f32_16x16x32_bf16(AL[mi], BH[j], acc[mi][ni], 0, 0, 0);
          acc[mi][ni] = __builtin_amdgcn_mfma_f32_16x16x32_bf16(AH[mi], BL[j], acc[mi][ni], 0, 0, 0);
        }
    }
    __syncthreads();
  }

#pragma unroll
  for (int mi = 0; mi < 2; ++mi)
#pragma unroll
    for (int ni = 0; ni < 8; ++ni) {
      int n = ni * 16 + l15;
      float b = bd[n];
#pragma unroll
      for (int r = 0; r < 4; ++r) {
        int m = mblk + wid * 32 + mi * 16 + quad * 4 + r;
        float v = lrelu(acc[mi][ni][r] + b, 0.01f);
        unsigned short hi = f2bf(v);
        unsigned short lo = f2bf(v - bf2f(hi));
        if (m < N) hp[(size_t)m * EMBED + n] = ((unsigned int)hi << 16) | lo;
      }
    }
}

// ---------------------------------------------------------------------------
// K2 v3: g = h @ Wg^T (+ in-wave att-dot epilogue), fp16 g store. (R8)
// ---------------------------------------------------------------------------
__global__ __launch_bounds__(256) void gemm2_mfma_kernel(
    const unsigned int* __restrict__ hp, const unsigned short* __restrict__ Wgh,
    const unsigned short* __restrict__ Wgl, const float* __restrict__ att_src,
    const float* __restrict__ att_dst, __half* __restrict__ gh,
    float* __restrict__ a_src, float* __restrict__ a_dst, int N) {
  __shared__ __align__(16) unsigned char Bhs[16384];  // 64 rows x 256 B
  __shared__ __align__(16) unsigned char Bls[16384];

  const int tid = threadIdx.x;
  const int lane = tid & 63;
  const int wid = tid >> 6;
  const int mblk = blockIdx.x * 128;
  const int quad = lane >> 4;
  const int l15 = lane & 15;

  const char* aptr[2];
#pragma unroll
  for (int mi = 0; mi < 2; ++mi) {
    int rg = mblk + wid * 32 + mi * 16 + l15;
    if (rg >= N) rg = N - 1;
    aptr[mi] = (const char*)hp + (size_t)rg * (EMBED * 4) + quad * 32;
  }
  uint4 areg[2][4][2];
#pragma unroll
  for (int mi = 0; mi < 2; ++mi)
#pragma unroll
    for (int ks = 0; ks < 4; ++ks) {
      areg[mi][ks][0] = *(const uint4*)(aptr[mi] + ks * 128);
      areg[mi][ks][1] = *(const uint4*)(aptr[mi] + ks * 128 + 16);
    }

#pragma unroll
  for (int i = 0; i < 4; ++i) {
    int chunk = i * 256 + tid;       // 0..1023
    int row = chunk >> 4, ch = chunk & 15;
    size_t srcoff = (size_t)row * (EMBED * 2) + ((ch ^ (row & 15)) << 4);
    gl_lds16((const char*)Wgh + srcoff, Bhs + chunk * 16);
    gl_lds16((const char*)Wgl + srcoff, Bls + chunk * 16);
  }
  __syncthreads();  // B resident; A regs complete (same vmcnt drain)

  f32x4 acc[2][4];
#pragma unroll
  for (int i = 0; i < 2; ++i)
#pragma unroll
    for (int j = 0; j < 4; ++j) acc[i][j] = (f32x4){0.f, 0.f, 0.f, 0.f};

#pragma unroll
  for (int ks = 0; ks < 4; ++ks) {
    bf16x8 AH[2], AL[2];
#pragma unroll
    for (int mi = 0; mi < 2; ++mi) {
      union { unsigned int u[8]; uint4 v[2]; } W_;
      W_.v[0] = areg[mi][ks][0];
      W_.v[1] = areg[mi][ks][1];
      union { unsigned int u[4]; bf16x8 v; } H, L;
#pragma unroll
      for (int p = 0; p < 4; ++p) {
        unsigned int wA = W_.u[2 * p], wB = W_.u[2 * p + 1];
        H.u[p] = __builtin_amdgcn_perm(wB, wA, 0x07060302u);  // hi16 pair
        L.u[p] = __builtin_amdgcn_perm(wB, wA, 0x05040100u);  // lo16 pair
      }
      AH[mi] = H.v;
      AL[mi] = L.v;
    }
#pragma unroll
    for (int ni = 0; ni < 4; ++ni) {
      int row = ni * 16 + l15;
      int chunk = ks * 4 + quad;
      int off = row * 256 + (((chunk ^ (row & 15))) << 4);
      bf16x8 BH = *(const bf16x8*)(Bhs + off);
      bf16x8 BL = *(const bf16x8*)(Bls + off);
#pragma unroll
      for (int mi = 0; mi < 2; ++mi) {
        acc[mi][ni] = __builtin_amdgcn_mfma_f32_16x16x32_bf16(AH[mi], BH, acc[mi][ni], 0, 0, 0);
        acc[mi][ni] = __builtin_amdgcn_mfma_f32_16x16x32_bf16(AL[mi], BH, acc[mi][ni], 0, 0, 0);
        acc[mi][ni] = __builtin_amdgcn_mfma_f32_16x16x32_bf16(AH[mi], BL, acc[mi][ni], 0, 0, 0);
      }
    }
  }

  float as_[4], ad_[4];
#pragma unroll
  for (int ni = 0; ni < 4; ++ni) {
    int n = ni * 16 + l15;
    as_[ni] = att_src[n];
    ad_[ni] = att_dst[n];
  }
#pragma unroll
  for (int mi = 0; mi < 2; ++mi) {
#pragma unroll
    for (int r = 0; r < 4; ++r) {
      int m = mblk + wid * 32 + mi * 16 + quad * 4 + r;
      float ps = acc[mi][0][r] * as_[0] + acc[mi][1][r] * as_[1] +
                 acc[mi][2][r] * as_[2] + acc[mi][3][r] * as_[3];
      float pd = acc[mi][0][r] * ad_[0] + acc[mi][1][r] * ad_[1] +
                 acc[mi][2][r] * ad_[2] + acc[mi][3][r] * ad_[3];
#pragma unroll
      for (int d = 1; d < 16; d <<= 1) {
        ps += __shfl_xor(ps, d, 64);
        pd += __shfl_xor(pd, d, 64);
      }
      if (m < N) {
#pragma unroll
        for (int ni = 0; ni < 4; ++ni)
          gh[(size_t)m * OUT_DIM + ni * 16 + l15] = __float2half(acc[mi][ni][r]);
        if (l15 == 0) {
          a_src[m] = ps;
          a_dst[m] = pd;
        }
      }
    }
  }
}

// ---------------------------------------------------------------------------
// Edge phase (deterministic software write-combining bin, parallel alloc)
// ---------------------------------------------------------------------------
__global__ __launch_bounds__(256) void hist_count_kernel(
    const int* __restrict__ ei, int* __restrict__ histT, int nblkP, int E,
    int N) {
  __shared__ int cnt[NBPAD];
  const int t = threadIdx.x;
  cnt[t] = 0;
  __syncthreads();
  const int T = E + N;
  const int base = blockIdx.x << SEGSH;
#pragma unroll
  for (int q = 0; q < (1 << SEGSH) / 256; ++q) {
    int i = base + q * 256 + t;
    if (i < T) {
      int d = (i < E) ? ei[E + i] : (i - E);
      atomicAdd(&cnt[d >> 8], 1);
    }
  }
  __syncthreads();
  histT[(size_t)t * nblkP + blockIdx.x] = cnt[t];
}

__global__ __launch_bounds__(256) void row_scan_kernel(
    int* __restrict__ histT, int* __restrict__ bucket_tot, int nblkP) {
  __shared__ int sc[256];
  const int t = threadIdx.x;
  int* row = histT + (size_t)blockIdx.x * nblkP;
  const int per = (nblkP + 255) / 256;
  int loc[8];
  int sum = 0;
#pragma unroll 4
  for (int j = 0; j < per; ++j) {
    int idx = t * per + j;
    int v = (idx < nblkP) ? row[idx] : 0;
    loc[j] = sum;
    sum += v;
  }
  sc[t] = sum;
  __syncthreads();
  for (int dlt = 1; dlt < 256; dlt <<= 1) {
    int add = (t >= dlt) ? sc[t - dlt] : 0;
    __syncthreads();
    sc[t] += add;
    __syncthreads();
  }
  const int off = sc[t] - sum;
#pragma unroll 4
  for (int j = 0; j < per; ++j) {
    int idx = t * per + j;
    if (idx < nblkP) row[idx] = off + loc[j];
  }
  if (t == 255) bucket_tot[blockIdx.x] = sc[255];
}

__global__ __launch_bounds__(256) void base_scan_kernel(
    const int* __restrict__ bucket_tot, int* __restrict__ bucket_base,
    int* __restrict__ offsets, int N, int T) {
  __shared__ int sc[256];
  const int t = threadIdx.x;
  int v = bucket_tot[t];
  sc[t] = v;
  __syncthreads();
  for (int dlt = 1; dlt < 256; dlt <<= 1) {
    int add = (t >= dlt) ? sc[t - dlt] : 0;
    __syncthreads();
    sc[t] += add;
    __syncthreads();
  }
  bucket_base[t] = sc[t] - v;
  if (t == 0) offsets[N] = T;
}

__global__ __launch_bounds__(256) void bin_kernel(
    const int* __restrict__ ei, const int* __restrict__ histT,
    const int* __restrict__ bucket_base, int* __restrict__ stageB, int nblkP,
    int E, int N) {
  __shared__ int cnt[NBPAD];
  __shared__ int basev[NBPAD];
  const int t = threadIdx.x;
  cnt[t] = 0;
  basev[t] = bucket_base[t] + histT[(size_t)t * nblkP + blockIdx.x];
  __syncthreads();
  const int T = E + N;
  const int base = blockIdx.x << SEGSH;
#pragma unroll
  for (int q = 0; q < (1 << SEGSH) / 256; ++q) {
    int i = base + q * 256 + t;
    if (i < T) {
      int s, d;
      if (i < E) {
        s = ei[i];
        d = ei[E + i];
      } else {
        s = d = i - E;
      }
      int b = d >> 8;
      int r = atomicAdd(&cnt[b], 1);
      stageB[basev[b] + r] = (s << 8) | (d & 255);
    }
  }
}

// ---------------------------------------------------------------------------
// build v2: CSR build + FULL softmax finalize. Per bucket (256 dests):
// pass A: per-dest count + scan. pass B: e, place (s,e) in LDS, record dl,
// atomicMax per-dest key. pass C: p = exp(e-m), atomicAdd per-dest l.
// pass D: write csr_pack = (s, p_unnorm), linv[d] = 1/l.
// aggregate then needs ONE pass and zero exp.
// ---------------------------------------------------------------------------
__global__ __launch_bounds__(256) void build_kernel(
    const int* __restrict__ stageB, const int* __restrict__ bucket_base,
    const int* __restrict__ bucket_tot, const float* __restrict__ a_src,
    const float* __restrict__ a_dst, int* __restrict__ offsets,
    int2* __restrict__ csr_pack, float* __restrict__ linv, int N) {
  __shared__ int cnt[256];
  __shared__ int pre[256];
  __shared__ int cur[256];
  __shared__ unsigned int mmax[256];
  __shared__ float lsum[256];
  __shared__ int2 buf[CAP_LDS];
  __shared__ unsigned char dlb[CAP_LDS];
  const int b = blockIdx.x;
  const int t = threadIdx.x;
  const int base = bucket_base[b];
  const int tot = bucket_tot[b];
  cnt[t] = 0;
  mmax[t] = 0u;     // fkey lower bound
  lsum[t] = 0.f;
  __syncthreads();
  const int* sp = stageB + base;
  for (int i = t; i < tot; i += 256) atomicAdd(&cnt[sp[i] & 255], 1);
  __syncthreads();
  int v = cnt[t];
  pre[t] = v;
  __syncthreads();
  for (int dlt = 1; dlt < 256; dlt <<= 1) {
    int add = (t >= dlt) ? pre[t - dlt] : 0;
    __syncthreads();
    pre[t] += add;
    __syncthreads();
  }
  const int excl = pre[t] - v;
  cur[t] = excl;
  const int d_self = (b << 8) | t;
  if (d_self < N) offsets[d_self] = base + excl;
  __syncthreads();
  // pass B: compute e, place, record dl, per-dest max
  for (int i = t; i < tot; i += 256) {
    int rec = sp[i];
    int dl = rec & 255;
    int s = rec >> 8;
    float e = a_src[s] + a_dst[(b << 8) | dl];
    e = e > 0.f ? e : 0.2f * e;  // leaky_relu(0.2)
    atomicMax(&mmax[dl], fkey(e));
    int pos = atomicAdd(&cur[dl], 1);
    int2 r2 = make_int2(s, __float_as_int(e));
    if (pos < CAP_LDS) {
      buf[pos] = r2;
      dlb[pos] = (unsigned char)dl;
    } else {
      csr_pack[base + pos] = r2;  // safety spill (+42 sigma: never; p unfixed)
    }
  }
  __syncthreads();
  const int lim = min(tot, CAP_LDS);
  // pass C: p = exp(e - m), accumulate l
  for (int i = t; i < lim; i += 256) {
    int dl = dlb[i];
    float m = funkey(mmax[dl]);
    float p = __expf(__int_as_float(buf[i].y) - m);
    buf[i].y = __float_as_int(p);
    atomicAdd(&lsum[dl], p);
  }
  __syncthreads();
  if (d_self < N) linv[d_self] = 1.f / lsum[t];  // self-loop => lsum > 0
  // pass D: write out (s, p_unnorm)
  for (int i = t; i < lim; i += 256) csr_pack[base + i] = buf[i];
}

// ---------------------------------------------------------------------------
// aggregate v4: SINGLE pass, zero exp. csr_pack holds (s, p_unnorm);
// out = (sum p*g[s]) * linv[node] + b.
// ---------------------------------------------------------------------------
__global__ __launch_bounds__(256) void aggregate_kernel(
    const int* __restrict__ offsets, const int2* __restrict__ csr_pack,
    const __half* __restrict__ gh, const float* __restrict__ linv,
    const float* __restrict__ b_gat, float* __restrict__ out, int N) {
  const int lane = threadIdx.x & 63;
  const int node = blockIdx.x * 4 + (threadIdx.x >> 6);
  if (node >= N) return;
  const int beg = offsets[node], end = offsets[node + 1];

  float acc0 = 0.f, acc1 = 0.f, acc2 = 0.f, acc3 = 0.f;
  for (int jb = beg; jb < end; jb += 64) {
    int j = jb + lane;
    float p = 0.f;
    int s = 0;
    if (j < end) {
      int2 rec = csr_pack[j];
      p = __int_as_float(rec.y);
      s = rec.x;
    }
    const int cnt = min(64, end - jb);
    int jj = 0;
    for (; jj + 4 <= cnt; jj += 4) {
      int s0 = __builtin_amdgcn_readlane(s, jj);
      int s1 = __builtin_amdgcn_readlane(s, jj + 1);
      int s2 = __builtin_amdgcn_readlane(s, jj + 2);
      int s3 = __builtin_amdgcn_readlane(s, jj + 3);
      float p0 = readlane_f(p, jj);
      float p1 = readlane_f(p, jj + 1);
      float p2 = readlane_f(p, jj + 2);
      float p3 = readlane_f(p, jj + 3);
      acc0 += p0 * __half2float(gh[((size_t)s0 << 6) + lane]);
      acc1 += p1 * __half2float(gh[((size_t)s1 << 6) + lane]);
      acc2 += p2 * __half2float(gh[((size_t)s2 << 6) + lane]);
      acc3 += p3 * __half2float(gh[((size_t)s3 << 6) + lane]);
    }
    for (; jj < cnt; ++jj) {
      int s0 = __builtin_amdgcn_readlane(s, jj);
      float p0 = readlane_f(p, jj);
      acc0 += p0 * __half2float(gh[((size_t)s0 << 6) + lane]);
    }
  }
  out[(size_t)node * OUT_DIM + lane] =
      ((acc0 + acc1) + (acc2 + acc3)) * linv[node] + b_gat[lane];
}

// ---------------------------------------------------------------------------
extern "C" void kernel_launch(void* const* d_in, const int* in_sizes, int n_in,
                              void* d_out, int out_size, void* d_ws, size_t ws_size,
                              hipStream_t stream) {
  const float* x = (const float*)d_in[0];
  const int* ei = (const int*)d_in[1];
  const float* Wd = (const float*)d_in[2];
  const float* bd = (const float*)d_in[3];
  const float* Wg = (const float*)d_in[4];
  const float* att_src = (const float*)d_in[5];
  const float* att_dst = (const float*)d_in[6];
  const float* bg = (const float*)d_in[7];
  float* out = (float*)d_out;

  const int N = in_sizes[0] / IN_DIM;
  const int E = in_sizes[1] / 2;
  const int T = E + N;
  const int NB = (N + 255) >> 8;                       // 196
  const int nblkP = (T + (1 << SEGSH) - 1) >> SEGSH;   // ~411

  char* ws = (char*)d_ws;
  size_t off = 0;
  auto alloc = [&](size_t bytes) -> void* {
    void* p = ws + off;
    off += (bytes + 15) & ~(size_t)15;
    return p;
  };
  unsigned int* hpk = (unsigned int*)alloc((size_t)N * EMBED * 4);
  __half* gh = (__half*)alloc((size_t)N * OUT_DIM * 2);
  float* a_src = (float*)alloc((size_t)N * 4);
  float* a_dst = (float*)alloc((size_t)N * 4);
  float* linv = (float*)alloc((size_t)N * 4);
  int* offsets = (int*)alloc((size_t)(N + 1) * 4);
  int* histT = (int*)alloc((size_t)NBPAD * nblkP * 4);
  int* bucket_base = (int*)alloc((size_t)NBPAD * 4);
  int* bucket_tot = (int*)alloc((size_t)NBPAD * 4);
  int* stageB = (int*)alloc((size_t)T * 4);
  int2* csr_pack = (int2*)alloc((size_t)T * 8);
  unsigned short* Wdh = (unsigned short*)alloc((size_t)EMBED * IN_DIM * 2);
  unsigned short* Wdl = (unsigned short*)alloc((size_t)EMBED * IN_DIM * 2);
  unsigned short* Wgh = (unsigned short*)alloc((size_t)OUT_DIM * EMBED * 2);
  unsigned short* Wgl = (unsigned short*)alloc((size_t)OUT_DIM * EMBED * 2);

  const int SPLIT_TOT = EMBED * IN_DIM + OUT_DIM * EMBED;  // 73728
  hipLaunchKernelGGL(split_w_kernel, dim3(SPLIT_TOT / 1024), dim3(256), 0,
                     stream, Wd, Wdh, Wdl, Wg, Wgh, Wgl);
  hipLaunchKernelGGL(gemm1_mfma_kernel, dim3((N + 127) / 128), dim3(256), 0,
                     stream, x, Wdh, Wdl, bd, hpk, N);
  hipLaunchKernelGGL(gemm2_mfma_kernel, dim3((N + 127) / 128), dim3(256), 0,
                     stream, hpk, Wgh, Wgl, att_src, att_dst, gh, a_src, a_dst, N);
  hipLaunchKernelGGL(hist_count_kernel, dim3(nblkP), dim3(256), 0, stream,
                     ei, histT, nblkP, E, N);
  hipLaunchKernelGGL(row_scan_kernel, dim3(NBPAD), dim3(256), 0, stream,
                     histT, bucket_tot, nblkP);
  hipLaunchKernelGGL(base_scan_kernel, dim3(1), dim3(256), 0, stream,
                     bucket_tot, bucket_base, offsets, N, T);
  hipLaunchKernelGGL(bin_kernel, dim3(nblkP), dim3(256), 0, stream,
                     ei, histT, bucket_base, stageB, nblkP, E, N);
  hipLaunchKernelGGL(build_kernel, dim3(NB), dim3(256), 0, stream,
                     stageB, bucket_base, bucket_tot, a_src, a_dst, offsets,
                     csr_pack, linv, N);
  hipLaunchKernelGGL(aggregate_kernel, dim3((N + 3) / 4), dim3(256), 0, stream,
                     offsets, csr_pack, gh, linv, bg, out, N);
}

// Round 10
// 295.920 us; speedup vs baseline: 1.0779x; 1.0779x over previous
//
#include <hip/hip_runtime.h>
#include <hip/hip_fp16.h>
#include <math.h>

#define IN_DIM 512
#define EMBED 128
#define OUT_DIM 64
#define NBPAD 256      // padded bucket count (actual NB = ceil(N/256) = 196)
#define SEGSH 12       // 4096 edges per bin block
#define CAP_LDS 10240  // build LDS capacity (mean 8430, +19 sigma)

typedef __attribute__((ext_vector_type(8))) short bf16x8;
typedef __attribute__((ext_vector_type(4))) float f32x4;

__device__ __forceinline__ float lrelu(float v, float s) { return v > 0.f ? v : v * s; }

__device__ __forceinline__ float readlane_f(float v, int l) {
  return __int_as_float(__builtin_amdgcn_readlane(__float_as_int(v), l));
}

__device__ __forceinline__ unsigned short f2bf(float f) {
  unsigned int u = __float_as_uint(f);
  u += 0x7fff + ((u >> 16) & 1);  // RTNE
  return (unsigned short)(u >> 16);
}
__device__ __forceinline__ float bf2f(unsigned short h) {
  return __uint_as_float(((unsigned int)h) << 16);
}

// packed f32x2 -> bf16x2 (low half = src0, high half = src1)
__device__ __forceinline__ unsigned int cvt_pk_bf16(float a, float b) {
  unsigned int r;
  asm("v_cvt_pk_bf16_f32 %0, %1, %2" : "=v"(r) : "v"(a), "v"(b));
  return r;
}

// async global->LDS 16B DMA (dest = wave base + lane*16, src per-lane)
__device__ __forceinline__ void gl_lds16(const void* g, void* l) {
  __builtin_amdgcn_global_load_lds(
      (const __attribute__((address_space(1))) unsigned int*)g,
      (__attribute__((address_space(3))) unsigned int*)l, 16, 0, 0);
}

// ---------------------------------------------------------------------------
// Prep: split Wd (65536) AND Wg (8192) fp32 -> bf16 hi/lo planes. One launch.
// ---------------------------------------------------------------------------
__global__ __launch_bounds__(256) void split_w_kernel(
    const float* __restrict__ Wd, unsigned short* __restrict__ Wdh,
    unsigned short* __restrict__ Wdl, const float* __restrict__ Wg,
    unsigned short* __restrict__ Wgh, unsigned short* __restrict__ Wgl) {
  int i = (blockIdx.x * 256 + threadIdx.x) * 4;
  const float* W;
  unsigned short *Wh, *Wl;
  int base;
  if (i < EMBED * IN_DIM) {
    W = Wd; Wh = Wdh; Wl = Wdl; base = i;
  } else {
    base = i - EMBED * IN_DIM;
    if (base >= OUT_DIM * EMBED) return;
    W = Wg; Wh = Wgh; Wl = Wgl;
  }
  float4 v = *(const float4*)(W + base);
  unsigned int h0 = cvt_pk_bf16(v.x, v.y);
  unsigned int h1 = cvt_pk_bf16(v.z, v.w);
  float r0 = v.x - __uint_as_float(h0 << 16);
  float r1 = v.y - __uint_as_float(h0 & 0xffff0000u);
  float r2 = v.z - __uint_as_float(h1 << 16);
  float r3 = v.w - __uint_as_float(h1 & 0xffff0000u);
  unsigned int l0 = cvt_pk_bf16(r0, r1);
  unsigned int l1 = cvt_pk_bf16(r2, r3);
  *(uint2*)(Wh + base) = make_uint2(h0, h1);
  *(uint2*)(Wl + base) = make_uint2(l0, l1);
}

// ---------------------------------------------------------------------------
// FUSED K1+K2: h = lrelu(x@Wd^T+bd) computed per 128-row block (R6 gemm1
// structure, unchanged math), then g = h@Wg^T + att-dots WITHOUT writing h
// to HBM. The dead 32KB B-dbuf is reused as a per-wave LDS transpose buffer
// (XOR-swizzled, 2-way = free both sides). Wg hi/lo planes (32KB) staged
// once at start via global_load_lds with the gemm2 swizzle. LDS 64KB.
// Per-element FP order identical to the previous gemm1+gemm2 pair.
// ---------------------------------------------------------------------------
__global__ __launch_bounds__(256) void gemm12_fused_kernel(
    const float* __restrict__ x, const unsigned short* __restrict__ Wdh,
    const unsigned short* __restrict__ Wdl, const float* __restrict__ bd,
    const unsigned short* __restrict__ Wgh, const unsigned short* __restrict__ Wgl,
    const float* __restrict__ att_src, const float* __restrict__ att_dst,
    __half* __restrict__ gh, float* __restrict__ a_src,
    float* __restrict__ a_dst, int N) {
  // [0,32768): K-loop B dbuf (hi: buf*8K, lo: 16K+buf*8K); later transpose
  // [32768,65536): Wg staged planes (hi at +0, lo at +16K)
  __shared__ __align__(16) unsigned char SMEM[65536];

  const int tid = threadIdx.x;
  const int lane = tid & 63;
  const int wid = tid >> 6;   // 0..3, wave owns rows wid*32..+32
  const int mblk = blockIdx.x * 128;
  const int quad = lane >> 4;
  const int l15 = lane & 15;

  // ---- A: direct global->reg, 2 rows per lane (mi=0,1), 32B/row/step ----
  const float* aptr[2];
#pragma unroll
  for (int mi = 0; mi < 2; ++mi) {
    int rg = mblk + wid * 32 + mi * 16 + l15;
    if (rg >= N) rg = N - 1;  // clamp; junk rows masked at store
    aptr[mi] = x + (size_t)rg * IN_DIM + quad * 8;
  }
  float4 tc[2][2];
  auto loadA = [&](int k0) {
#pragma unroll
    for (int mi = 0; mi < 2; ++mi) {
      tc[mi][0] = *(const float4*)(aptr[mi] + k0);
      tc[mi][1] = *(const float4*)(aptr[mi] + k0 + 4);
    }
  };

  // ---- Wd staging (K-loop dbuf): 2 hi + 2 lo 16B chunks/thread/step ----
  const char* bsrcH[2];
  const char* bsrcL[2];
  int bdst[2];
#pragma unroll
  for (int i = 0; i < 2; ++i) {
    int chunk = i * 256 + tid;
    int row = chunk >> 2, ch = chunk & 3;
    int cs = ch ^ ((row >> 1) & 3);  // inverse-swizzled source chunk
    size_t srcoff = (size_t)row * (IN_DIM * 2) + (cs << 4);
    bsrcH[i] = (const char*)Wdh + srcoff;
    bsrcL[i] = (const char*)Wdl + srcoff;
    bdst[i] = chunk * 16;
  }
  auto stageB = [&](int buf, int k0) {
    const size_t kb = (size_t)k0 * 2;
#pragma unroll
    for (int i = 0; i < 2; ++i) {
      gl_lds16(bsrcH[i] + kb, SMEM + buf * 8192 + bdst[i]);
      gl_lds16(bsrcL[i] + kb, SMEM + 16384 + buf * 8192 + bdst[i]);
    }
  };

  int boff[8];
#pragma unroll
  for (int ni = 0; ni < 8; ++ni) {
    int row = ni * 16 + l15;
    boff[ni] = row * 64 + ((quad ^ ((row >> 1) & 3)) << 4);
  }

  f32x4 acc[2][8];
#pragma unroll
  for (int i = 0; i < 2; ++i)
#pragma unroll
    for (int j = 0; j < 8; ++j) acc[i][j] = (f32x4){0.f, 0.f, 0.f, 0.f};

  // ---- stage Wg planes once (gemm2 swizzle), + first Wd tile + A ----
#pragma unroll
  for (int i = 0; i < 4; ++i) {
    int chunk = i * 256 + tid;       // 0..1023
    int row = chunk >> 4, ch = chunk & 15;
    size_t srcoff = (size_t)row * (EMBED * 2) + ((ch ^ (row & 15)) << 4);
    gl_lds16((const char*)Wgh + srcoff, SMEM + 32768 + chunk * 16);
    gl_lds16((const char*)Wgl + srcoff, SMEM + 49152 + chunk * 16);
  }
  stageB(0, 0);
  loadA(0);
  __syncthreads();

  // ---- K-loop (identical to R6/R8 gemm1) ----
#pragma unroll 2
  for (int s = 0; s < IN_DIM / 32; ++s) {
    const int buf = s & 1;
    if (s + 1 < IN_DIM / 32) stageB(buf ^ 1, (s + 1) * 32);

    bf16x8 AH[2], AL[2];
#pragma unroll
    for (int mi = 0; mi < 2; ++mi) {
      float av[8] = {tc[mi][0].x, tc[mi][0].y, tc[mi][0].z, tc[mi][0].w,
                     tc[mi][1].x, tc[mi][1].y, tc[mi][1].z, tc[mi][1].w};
      union { unsigned int u[4]; bf16x8 v; } H, L;
#pragma unroll
      for (int i = 0; i < 4; ++i) {
        unsigned int hpk = cvt_pk_bf16(av[2 * i], av[2 * i + 1]);
        float q0 = av[2 * i] - __uint_as_float(hpk << 16);
        float q1 = av[2 * i + 1] - __uint_as_float(hpk & 0xffff0000u);
        H.u[i] = hpk;
        L.u[i] = cvt_pk_bf16(q0, q1);
      }
      AH[mi] = H.v;
      AL[mi] = L.v;
    }
    if (s + 1 < IN_DIM / 32) loadA((s + 1) * 32);

#pragma unroll
    for (int hf = 0; hf < 2; ++hf) {
      bf16x8 BH[4], BL[4];
#pragma unroll
      for (int j = 0; j < 4; ++j) {
        BH[j] = *(const bf16x8*)(SMEM + buf * 8192 + boff[hf * 4 + j]);
        BL[j] = *(const bf16x8*)(SMEM + 16384 + buf * 8192 + boff[hf * 4 + j]);
      }
#pragma unroll
      for (int mi = 0; mi < 2; ++mi)
#pragma unroll
        for (int j = 0; j < 4; ++j) {
          int ni = hf * 4 + j;
          acc[mi][ni] = __builtin_amdgcn_mfma_f32_16x16x32_bf16(AH[mi], BH[j], acc[mi][ni], 0, 0, 0);
          acc[mi][ni] = __builtin_amdgcn_mfma_f32_16x16x32_bf16(AL[mi], BH[j], acc[mi][ni], 0, 0, 0);
          acc[mi][ni] = __builtin_amdgcn_mfma_f32_16x16x32_bf16(AH[mi], BL[j], acc[mi][ni], 0, 0, 0);
        }
    }
    __syncthreads();
  }

  // ---- fused second GEMM: per mi, LDS-transpose h then 48 MFMAs ----
  unsigned char* Tr = SMEM;                       // dbuf is dead now
  const unsigned char* WgHs = SMEM + 32768;
  const unsigned char* WgLs = SMEM + 49152;

  f32x4 acc2[2][4];
#pragma unroll
  for (int i = 0; i < 2; ++i)
#pragma unroll
    for (int j = 0; j < 4; ++j) acc2[i][j] = (f32x4){0.f, 0.f, 0.f, 0.f};

#pragma unroll
  for (int mi = 0; mi < 2; ++mi) {
    __syncthreads();  // Tr region free (prev use complete)
    // pack h (bias+lrelu, split-bf16) -> swizzled transpose store (2-way)
#pragma unroll
    for (int ni = 0; ni < 8; ++ni) {
      int n = ni * 16 + l15;
      float b = bd[n];
#pragma unroll
      for (int r = 0; r < 4; ++r) {
        float v = lrelu(acc[mi][ni][r] + b, 0.01f);
        unsigned short hi = f2bf(v);
        unsigned short lo = f2bf(v - bf2f(hi));
        unsigned int pw = ((unsigned int)hi << 16) | lo;
        int row16 = quad * 4 + r;            // row within wave's 16-row slab
        int col = ni * 16 + l15;             // k index 0..127
        int cc = col >> 2;                   // 16B chunk 0..31
        int cs = cc ^ (row16 & 7);           // swizzle
        *(unsigned int*)(Tr + wid * 8192 + row16 * 512 + cs * 16 +
                         (col & 3) * 4) = pw;
      }
    }
    __syncthreads();
    // A-fragments from Tr, B from WgS; order identical to old gemm2
#pragma unroll
    for (int ks = 0; ks < 4; ++ks) {
      const int s7 = l15 & 7;
      const int cc0 = ks * 8 + quad * 2;
      const unsigned char* tb = Tr + wid * 8192 + l15 * 512;
      union { unsigned int u[8]; uint4 v[2]; } W_;
      W_.v[0] = *(const uint4*)(tb + ((cc0 ^ s7) << 4));
      W_.v[1] = *(const uint4*)(tb + (((cc0 + 1) ^ s7) << 4));
      union { unsigned int u[4]; bf16x8 v; } H, L;
#pragma unroll
      for (int p = 0; p < 4; ++p) {
        unsigned int wA = W_.u[2 * p], wB = W_.u[2 * p + 1];
        H.u[p] = __builtin_amdgcn_perm(wB, wA, 0x07060302u);  // hi16 pair
        L.u[p] = __builtin_amdgcn_perm(wB, wA, 0x05040100u);  // lo16 pair
      }
      bf16x8 AH2 = H.v, AL2 = L.v;
#pragma unroll
      for (int ni = 0; ni < 4; ++ni) {
        int row = ni * 16 + l15;
        int chunk = ks * 4 + quad;
        int off = row * 256 + (((chunk ^ (row & 15))) << 4);
        bf16x8 BH = *(const bf16x8*)(WgHs + off);
        bf16x8 BL = *(const bf16x8*)(WgLs + off);
        acc2[mi][ni] = __builtin_amdgcn_mfma_f32_16x16x32_bf16(AH2, BH, acc2[mi][ni], 0, 0, 0);
        acc2[mi][ni] = __builtin_amdgcn_mfma_f32_16x16x32_bf16(AL2, BH, acc2[mi][ni], 0, 0, 0);
        acc2[mi][ni] = __builtin_amdgcn_mfma_f32_16x16x32_bf16(AH2, BL, acc2[mi][ni], 0, 0, 0);
      }
    }
  }

  // ---- epilogue: fp16 g store + in-wave att dots (gemm2's, verbatim) ----
  float as_[4], ad_[4];
#pragma unroll
  for (int ni = 0; ni < 4; ++ni) {
    int n = ni * 16 + l15;
    as_[ni] = att_src[n];
    ad_[ni] = att_dst[n];
  }
#pragma unroll
  for (int mi = 0; mi < 2; ++mi) {
#pragma unroll
    for (int r = 0; r < 4; ++r) {
      int m = mblk + wid * 32 + mi * 16 + quad * 4 + r;
      float ps = acc2[mi][0][r] * as_[0] + acc2[mi][1][r] * as_[1] +
                 acc2[mi][2][r] * as_[2] + acc2[mi][3][r] * as_[3];
      float pd = acc2[mi][0][r] * ad_[0] + acc2[mi][1][r] * ad_[1] +
                 acc2[mi][2][r] * ad_[2] + acc2[mi][3][r] * ad_[3];
#pragma unroll
      for (int d = 1; d < 16; d <<= 1) {
        ps += __shfl_xor(ps, d, 64);
        pd += __shfl_xor(pd, d, 64);
      }
      if (m < N) {
#pragma unroll
        for (int ni = 0; ni < 4; ++ni)
          gh[(size_t)m * OUT_DIM + ni * 16 + l15] = __float2half(acc2[mi][ni][r]);
        if (l15 == 0) {
          a_src[m] = ps;
          a_dst[m] = pd;
        }
      }
    }
  }
}

// ---------------------------------------------------------------------------
// Edge phase (deterministic software write-combining bin, parallel alloc)
// ---------------------------------------------------------------------------
__global__ __launch_bounds__(256) void hist_count_kernel(
    const int* __restrict__ ei, int* __restrict__ histT, int nblkP, int E,
    int N) {
  __shared__ int cnt[NBPAD];
  const int t = threadIdx.x;
  cnt[t] = 0;
  __syncthreads();
  const int T = E + N;
  const int base = blockIdx.x << SEGSH;
#pragma unroll
  for (int q = 0; q < (1 << SEGSH) / 256; ++q) {
    int i = base + q * 256 + t;
    if (i < T) {
      int d = (i < E) ? ei[E + i] : (i - E);
      atomicAdd(&cnt[d >> 8], 1);
    }
  }
  __syncthreads();
  histT[(size_t)t * nblkP + blockIdx.x] = cnt[t];
}

__global__ __launch_bounds__(256) void row_scan_kernel(
    int* __restrict__ histT, int* __restrict__ bucket_tot, int nblkP) {
  __shared__ int sc[256];
  const int t = threadIdx.x;
  int* row = histT + (size_t)blockIdx.x * nblkP;
  const int per = (nblkP + 255) / 256;
  int loc[8];
  int sum = 0;
#pragma unroll 4
  for (int j = 0; j < per; ++j) {
    int idx = t * per + j;
    int v = (idx < nblkP) ? row[idx] : 0;
    loc[j] = sum;
    sum += v;
  }
  sc[t] = sum;
  __syncthreads();
  for (int dlt = 1; dlt < 256; dlt <<= 1) {
    int add = (t >= dlt) ? sc[t - dlt] : 0;
    __syncthreads();
    sc[t] += add;
    __syncthreads();
  }
  const int off = sc[t] - sum;
#pragma unroll 4
  for (int j = 0; j < per; ++j) {
    int idx = t * per + j;
    if (idx < nblkP) row[idx] = off + loc[j];
  }
  if (t == 255) bucket_tot[blockIdx.x] = sc[255];
}

__global__ __launch_bounds__(256) void base_scan_kernel(
    const int* __restrict__ bucket_tot, int* __restrict__ bucket_base,
    int* __restrict__ offsets, int N, int T) {
  __shared__ int sc[256];
  const int t = threadIdx.x;
  int v = bucket_tot[t];
  sc[t] = v;
  __syncthreads();
  for (int dlt = 1; dlt < 256; dlt <<= 1) {
    int add = (t >= dlt) ? sc[t - dlt] : 0;
    __syncthreads();
    sc[t] += add;
    __syncthreads();
  }
  bucket_base[t] = sc[t] - v;
  if (t == 0) offsets[N] = T;
}

__global__ __launch_bounds__(256) void bin_kernel(
    const int* __restrict__ ei, const int* __restrict__ histT,
    const int* __restrict__ bucket_base, int* __restrict__ stageB, int nblkP,
    int E, int N) {
  __shared__ int cnt[NBPAD];
  __shared__ int basev[NBPAD];
  const int t = threadIdx.x;
  cnt[t] = 0;
  basev[t] = bucket_base[t] + histT[(size_t)t * nblkP + blockIdx.x];
  __syncthreads();
  const int T = E + N;
  const int base = blockIdx.x << SEGSH;
#pragma unroll
  for (int q = 0; q < (1 << SEGSH) / 256; ++q) {
    int i = base + q * 256 + t;
    if (i < T) {
      int s, d;
      if (i < E) {
        s = ei[i];
        d = ei[E + i];
      } else {
        s = d = i - E;
      }
      int b = d >> 8;
      int r = atomicAdd(&cnt[b], 1);
      stageB[basev[b] + r] = (s << 8) | (d & 255);
    }
  }
}

__global__ __launch_bounds__(256) void build_kernel(
    const int* __restrict__ stageB, const int* __restrict__ bucket_base,
    const int* __restrict__ bucket_tot, const float* __restrict__ a_src,
    const float* __restrict__ a_dst, int* __restrict__ offsets,
    int2* __restrict__ csr_pack, int N) {
  __shared__ int cnt[256];
  __shared__ int pre[256];
  __shared__ int cur[256];
  __shared__ int2 buf[CAP_LDS];
  const int b = blockIdx.x;
  const int t = threadIdx.x;
  const int base = bucket_base[b];
  const int tot = bucket_tot[b];
  cnt[t] = 0;
  __syncthreads();
  const int* sp = stageB + base;
  for (int i = t; i < tot; i += 256) atomicAdd(&cnt[sp[i] & 255], 1);
  __syncthreads();
  int v = cnt[t];
  pre[t] = v;
  __syncthreads();
  for (int dlt = 1; dlt < 256; dlt <<= 1) {
    int add = (t >= dlt) ? pre[t - dlt] : 0;
    __syncthreads();
    pre[t] += add;
    __syncthreads();
  }
  const int excl = pre[t] - v;
  cur[t] = excl;
  const int d_self = (b << 8) | t;
  if (d_self < N) offsets[d_self] = base + excl;
  __syncthreads();
  for (int i = t; i < tot; i += 256) {
    int rec = sp[i];
    int dl = rec & 255;
    int s = rec >> 8;
    float e = a_src[s] + a_dst[(b << 8) | dl];
    e = e > 0.f ? e : 0.2f * e;  // leaky_relu(0.2)
    int pos = atomicAdd(&cur[dl], 1);
    int2 r2 = make_int2(s, __float_as_int(e));
    if (pos < CAP_LDS)
      buf[pos] = r2;
    else
      csr_pack[base + pos] = r2;  // safety spill (statistically never)
  }
  __syncthreads();
  const int lim = min(tot, CAP_LDS);
  for (int i = t; i < lim; i += 256) csr_pack[base + i] = buf[i];
}

// ---------------------------------------------------------------------------
// one wave per node, lane = output dim; readlane-broadcast aggregation.
// online (m,l) single pass; g gathered as fp16. (R8 version, best measured)
// ---------------------------------------------------------------------------
__global__ __launch_bounds__(256) void aggregate_kernel(
    const int* __restrict__ offsets, const int2* __restrict__ csr_pack,
    const __half* __restrict__ gh, const float* __restrict__ b_gat,
    float* __restrict__ out, int N) {
  const int lane = threadIdx.x & 63;
  const int node = blockIdx.x * 4 + (threadIdx.x >> 6);
  if (node >= N) return;
  const int beg = offsets[node], end = offsets[node + 1];

  // online (m,l) per lane over strided records
  float m = -1e30f, l = 0.f;
  for (int j = beg + lane; j < end; j += 64) {
    float e = __int_as_float(csr_pack[j].y);
    if (e > m) {
      l = l * __expf(m - e) + 1.f;
      m = e;
    } else {
      l += __expf(e - m);
    }
  }
  // butterfly combine of (m,l) pairs
#pragma unroll
  for (int d = 1; d < 64; d <<= 1) {
    float mo = __shfl_xor(m, d, 64);
    float lo = __shfl_xor(l, d, 64);
    float M = fmaxf(m, mo);
    l = l * __expf(m - M) + lo * __expf(mo - M);
    m = M;
  }
  const float inv_l = 1.f / l;

  float acc0 = 0.f, acc1 = 0.f, acc2 = 0.f, acc3 = 0.f;
  for (int jb = beg; jb < end; jb += 64) {
    int j = jb + lane;
    float p = 0.f;
    int s = 0;
    if (j < end) {
      int2 rec = csr_pack[j];
      p = __expf(__int_as_float(rec.y) - m) * inv_l;
      s = rec.x;
    }
    const int cnt = min(64, end - jb);
    int jj = 0;
    for (; jj + 4 <= cnt; jj += 4) {
      int s0 = __builtin_amdgcn_readlane(s, jj);
      int s1 = __builtin_amdgcn_readlane(s, jj + 1);
      int s2 = __builtin_amdgcn_readlane(s, jj + 2);
      int s3 = __builtin_amdgcn_readlane(s, jj + 3);
      float p0 = readlane_f(p, jj);
      float p1 = readlane_f(p, jj + 1);
      float p2 = readlane_f(p, jj + 2);
      float p3 = readlane_f(p, jj + 3);
      acc0 += p0 * __half2float(gh[((size_t)s0 << 6) + lane]);
      acc1 += p1 * __half2float(gh[((size_t)s1 << 6) + lane]);
      acc2 += p2 * __half2float(gh[((size_t)s2 << 6) + lane]);
      acc3 += p3 * __half2float(gh[((size_t)s3 << 6) + lane]);
    }
    for (; jj < cnt; ++jj) {
      int s0 = __builtin_amdgcn_readlane(s, jj);
      float p0 = readlane_f(p, jj);
      acc0 += p0 * __half2float(gh[((size_t)s0 << 6) + lane]);
    }
  }
  out[(size_t)node * OUT_DIM + lane] = (acc0 + acc1) + (acc2 + acc3) + b_gat[lane];
}

// ---------------------------------------------------------------------------
extern "C" void kernel_launch(void* const* d_in, const int* in_sizes, int n_in,
                              void* d_out, int out_size, void* d_ws, size_t ws_size,
                              hipStream_t stream) {
  const float* x = (const float*)d_in[0];
  const int* ei = (const int*)d_in[1];
  const float* Wd = (const float*)d_in[2];
  const float* bd = (const float*)d_in[3];
  const float* Wg = (const float*)d_in[4];
  const float* att_src = (const float*)d_in[5];
  const float* att_dst = (const float*)d_in[6];
  const float* bg = (const float*)d_in[7];
  float* out = (float*)d_out;

  const int N = in_sizes[0] / IN_DIM;
  const int E = in_sizes[1] / 2;
  const int T = E + N;
  const int NB = (N + 255) >> 8;                       // 196
  const int nblkP = (T + (1 << SEGSH) - 1) >> SEGSH;   // ~411

  char* ws = (char*)d_ws;
  size_t off = 0;
  auto alloc = [&](size_t bytes) -> void* {
    void* p = ws + off;
    off += (bytes + 15) & ~(size_t)15;
    return p;
  };
  __half* gh = (__half*)alloc((size_t)N * OUT_DIM * 2);
  float* a_src = (float*)alloc((size_t)N * 4);
  float* a_dst = (float*)alloc((size_t)N * 4);
  int* offsets = (int*)alloc((size_t)(N + 1) * 4);
  int* histT = (int*)alloc((size_t)NBPAD * nblkP * 4);
  int* bucket_base = (int*)alloc((size_t)NBPAD * 4);
  int* bucket_tot = (int*)alloc((size_t)NBPAD * 4);
  int* stageB = (int*)alloc((size_t)T * 4);
  int2* csr_pack = (int2*)alloc((size_t)T * 8);
  unsigned short* Wdh = (unsigned short*)alloc((size_t)EMBED * IN_DIM * 2);
  unsigned short* Wdl = (unsigned short*)alloc((size_t)EMBED * IN_DIM * 2);
  unsigned short* Wgh = (unsigned short*)alloc((size_t)OUT_DIM * EMBED * 2);
  unsigned short* Wgl = (unsigned short*)alloc((size_t)OUT_DIM * EMBED * 2);

  const int SPLIT_TOT = EMBED * IN_DIM + OUT_DIM * EMBED;  // 73728
  hipLaunchKernelGGL(split_w_kernel, dim3(SPLIT_TOT / 1024), dim3(256), 0,
                     stream, Wd, Wdh, Wdl, Wg, Wgh, Wgl);
  hipLaunchKernelGGL(gemm12_fused_kernel, dim3((N + 127) / 128), dim3(256), 0,
                     stream, x, Wdh, Wdl, bd, Wgh, Wgl, att_src, att_dst,
                     gh, a_src, a_dst, N);
  hipLaunchKernelGGL(hist_count_kernel, dim3(nblkP), dim3(256), 0, stream,
                     ei, histT, nblkP, E, N);
  hipLaunchKernelGGL(row_scan_kernel, dim3(NBPAD), dim3(256), 0, stream,
                     histT, bucket_tot, nblkP);
  hipLaunchKernelGGL(base_scan_kernel, dim3(1), dim3(256), 0, stream,
                     bucket_tot, bucket_base, offsets, N, T);
  hipLaunchKernelGGL(bin_kernel, dim3(nblkP), dim3(256), 0, stream,
                     ei, histT, bucket_base, stageB, nblkP, E, N);
  hipLaunchKernelGGL(build_kernel, dim3(NB), dim3(256), 0, stream,
                     stageB, bucket_base, bucket_tot, a_src, a_dst, offsets,
                     csr_pack, N);
  hipLaunchKernelGGL(aggregate_kernel, dim3((N + 3) / 4), dim3(256), 0, stream,
                     offsets, csr_pack, gh, bg, out, N);
}